// Round 6
// baseline (71528.381 us; speedup 1.0000x reference)
//
#include <hip/hip_runtime.h>
#include <hip/hip_bf16.h>
#include <math.h>

#define D 512
#define H 512
#define G3 1536
#define GRU_WGS 32
#define GRU_THREADS 512   // 8 waves/WG ; 256 waves total, 2 h-elements each

__device__ __forceinline__ float sigmoidf_(float x) {
    return __fdividef(1.0f, 1.0f + __expf(-x));
}
__device__ __forceinline__ float tanhf_(float x) {
    return 1.0f - 2.0f * __fdividef(1.0f, 1.0f + __expf(2.0f * x));
}

// ---------------- degree / norm ----------------
__global__ void deg_init(float* deg, int N) {
    int i = blockIdx.x * blockDim.x + threadIdx.x;
    if (i < N) deg[i] = 2.0f;   // two self loops per node
}
__global__ void deg_count(const int* __restrict__ ei, float* deg, int E) {
    int e = blockIdx.x * blockDim.x + threadIdx.x;
    if (e < E) atomicAdd(&deg[ei[E + e]], 1.0f);
}
__global__ void deg_inv(const float* __restrict__ deg, float* dinv, int N) {
    int i = blockIdx.x * blockDim.x + threadIdx.x;
    if (i < N) dinv[i] = rsqrtf(deg[i]);
}

// ---------------- f32 tiled GEMM ----------------
template<bool NT, bool BIAS>
__global__ __launch_bounds__(256) void gemm64(
    const float* __restrict__ A, const float* __restrict__ B,
    const float* __restrict__ bias, float* __restrict__ C,
    int M, int N, int K)
{
    __shared__ float As[16][68];
    __shared__ float Bs[16][68];
    const int tid = threadIdx.x;
    const int tx = tid & 15, ty = tid >> 4;
    const int bm = blockIdx.y * 64, bn = blockIdx.x * 64;
    float acc[4][4] = {};
    for (int k0 = 0; k0 < K; k0 += 16) {
        #pragma unroll
        for (int l = 0; l < 4; ++l) {
            int idx = tid + l * 256;
            int m = idx >> 4, kk = idx & 15;
            As[kk][m] = A[(size_t)(bm + m) * K + (k0 + kk)];
            if (NT) {
                int n = idx >> 4, k2 = idx & 15;
                Bs[k2][n] = B[(size_t)(bn + n) * K + (k0 + k2)];
            } else {
                int k2 = idx >> 6, n = idx & 63;
                Bs[k2][n] = B[(size_t)(k0 + k2) * N + (bn + n)];
            }
        }
        __syncthreads();
        #pragma unroll
        for (int kk = 0; kk < 16; ++kk) {
            float4 av = *(const float4*)&As[kk][ty * 4];
            float4 bv = *(const float4*)&Bs[kk][tx * 4];
            float a[4] = {av.x, av.y, av.z, av.w};
            float b[4] = {bv.x, bv.y, bv.z, bv.w};
            #pragma unroll
            for (int i = 0; i < 4; ++i)
                #pragma unroll
                for (int j = 0; j < 4; ++j)
                    acc[i][j] = fmaf(a[i], b[j], acc[i][j]);
        }
        __syncthreads();
    }
    #pragma unroll
    for (int i = 0; i < 4; ++i)
        #pragma unroll
        for (int j = 0; j < 4; ++j) {
            float v = acc[i][j];
            if (BIAS) v += bias[bn + tx * 4 + j];
            C[(size_t)(bm + ty * 4 + i) * N + (bn + tx * 4 + j)] = v;
        }
}

// ---------------- GCN aggregation ----------------
__global__ void gcn_init(const float* __restrict__ xw, const float* __restrict__ dinv,
                         const float* __restrict__ bias, float* __restrict__ gcn, int N) {
    int n = blockIdx.x;
    int k = threadIdx.x;
    float di = dinv[n];
    gcn[(size_t)n * D + k] = bias[k] + 2.0f * di * di * xw[(size_t)n * D + k];
}
__global__ void scatter_edges(const int* __restrict__ ei, const float* __restrict__ xw,
                              const float* __restrict__ dinv, float* __restrict__ gcn, int E) {
    int e = blockIdx.x;
    int row = ei[e], col = ei[E + e];
    float norm = dinv[row] * dinv[col];
    int k = threadIdx.x;
    atomicAdd(&gcn[(size_t)col * D + k], norm * xw[(size_t)row * D + k]);
}

// ---------------- GRU ----------------
// h exchange: hx[2][512] of u32. Value = f32 h with its 2 mantissa LSBs
// replaced by (step_tag & 3). With the 2-slot protocol the only tags ever
// observable at a word during a poll for step t are {t-2, t} (mod 4 these
// differ by 2), so 2 tag bits suffice and each 4B word is self-validating
// -> single dword loads/stores, no fences, no tearing concerns.
// Tag-bit noise in h is <= 4.8e-7 (harmless vs f16-level threshold 4.45e-3).
__global__ void gru_init(const float* __restrict__ hidden, unsigned* hx) {
    int i = threadIdx.x;           // 512 threads
    hx[i] = __float_as_uint(hidden[i]) & ~3u;  // slot 0: h_0, tag 0
    hx[H + i] = 2u;                            // slot 1: tag 2, never matches tag 1
}

// 32 WGs x 512 threads = 256 waves. Wave (wg,wid) owns elements
// e0=wg*16+2*wid, e0+1 and the 6 rows {g*512+e} of w_hh in registers.
// Zero barriers, zero LDS: dots reduce in-wave, gates+publish in lane 0,
// h_old carried in lane-0 registers.
__global__ __launch_bounds__(GRU_THREADS, 1) void gru_kernel(
    const float* __restrict__ gi, const float* __restrict__ w_hh,
    const float* __restrict__ b_hh, unsigned* hx,
    float* __restrict__ out, int T)
{
    const int wg = blockIdx.x;
    const int tid = threadIdx.x;
    const int wid = tid >> 6;
    const int lane = tid & 63;
    const int e0 = wg * 16 + 2 * wid;   // first of this wave's 2 elements

    // rows r: gate g=r>>1 (0=r,1=z,2=n), element offset r&1
    float w_reg[6][8];
    float bhh[6];
    #pragma unroll
    for (int r = 0; r < 6; ++r) {
        int grow = (r >> 1) * H + e0 + (r & 1);
        bhh[r] = b_hh[grow];
        #pragma unroll
        for (int m = 0; m < 8; ++m)
            w_reg[r][m] = w_hh[(size_t)grow * H + lane + 64 * m];
    }

    // lane-0 carried state: previous h for my 2 elements + current-step gi.
    // Seed words in hx slot 0 have zero tag bits (exact h_0 values).
    float hold0 = __uint_as_float(hx[e0]);
    float hold1 = __uint_as_float(hx[e0 + 1]);
    float2 g_r = *(const float2*)&gi[e0];
    float2 g_z = *(const float2*)&gi[H + e0];
    float2 g_n = *(const float2*)&gi[2 * H + e0];

    for (int t = 0; t < T; ++t) {
        // ---- consume h_t: per-lane direct poll of 8 tagged words ----
        const unsigned* hs = hx + (t & 1) * H;
        const unsigned want = (unsigned)t & 3u;
        unsigned vv[8];
        #pragma unroll
        for (int m = 0; m < 8; ++m)
            vv[m] = __hip_atomic_load(&hs[lane + 64 * m], __ATOMIC_RELAXED,
                                      __HIP_MEMORY_SCOPE_AGENT);
        for (;;) {
            bool ok = true;
            #pragma unroll
            for (int m = 0; m < 8; ++m) ok &= ((vv[m] & 3u) == want);
            if (__all(ok)) break;
            __builtin_amdgcn_s_sleep(1);
            #pragma unroll
            for (int m = 0; m < 8; ++m)
                if ((vv[m] & 3u) != want)
                    vv[m] = __hip_atomic_load(&hs[lane + 64 * m], __ATOMIC_RELAXED,
                                              __HIP_MEMORY_SCOPE_AGENT);
        }

        // ---- 6 dots: per-lane partials then 6-level butterfly ----
        float acc[6];
        #pragma unroll
        for (int r = 0; r < 6; ++r) {
            float s = 0.f;
            #pragma unroll
            for (int m = 0; m < 8; ++m)
                s = fmaf(w_reg[r][m], __uint_as_float(vv[m]), s);
            acc[r] = s;
        }
        #pragma unroll
        for (int off = 32; off; off >>= 1) {
            #pragma unroll
            for (int r = 0; r < 6; ++r)
                acc[r] += __shfl_xor(acc[r], off, 64);
        }

        // ---- lane 0: gates for 2 elements, publish, out, gi prefetch ----
        if (lane == 0) {
            // issue next-step gi loads first (overlap with gate math)
            float2 ngr, ngz, ngn;
            if (t + 1 < T) {
                const float* gb2 = gi + (size_t)(t + 1) * G3;
                ngr = *(const float2*)&gb2[e0];
                ngz = *(const float2*)&gb2[H + e0];
                ngn = *(const float2*)&gb2[2 * H + e0];
            } else { ngr = g_r; ngz = g_z; ngn = g_n; }

            float rg0 = sigmoidf_(g_r.x + acc[0] + bhh[0]);
            float rg1 = sigmoidf_(g_r.y + acc[1] + bhh[1]);
            float zg0 = sigmoidf_(g_z.x + acc[2] + bhh[2]);
            float zg1 = sigmoidf_(g_z.y + acc[3] + bhh[3]);
            float ng0 = tanhf_(g_n.x + rg0 * (acc[4] + bhh[4]));
            float ng1 = tanhf_(g_n.y + rg1 * (acc[5] + bhh[5]));
            float h0 = ng0 + zg0 * (hold0 - ng0);
            float h1 = ng1 + zg1 * (hold1 - ng1);

            unsigned p0 = (__float_as_uint(h0) & ~3u) | ((unsigned)(t + 1) & 3u);
            unsigned p1 = (__float_as_uint(h1) & ~3u) | ((unsigned)(t + 1) & 3u);
            unsigned long long pv = ((unsigned long long)p1 << 32) | p0;
            __hip_atomic_store((unsigned long long*)&hx[((t + 1) & 1) * H + e0], pv,
                               __ATOMIC_RELAXED, __HIP_MEMORY_SCOPE_AGENT);

            *(float2*)&out[(size_t)t * H + e0] = make_float2(h0, h1);
            if (t == T - 1)
                *(float2*)&out[(size_t)T * H + e0] = make_float2(h0, h1);

            hold0 = h0; hold1 = h1;
            g_r = ngr; g_z = ngz; g_n = ngn;
        }
    }
}

// ---------------- launcher ----------------
extern "C" void kernel_launch(void* const* d_in, const int* in_sizes, int n_in,
                              void* d_out, int out_size, void* d_ws, size_t ws_size,
                              hipStream_t stream) {
    const float* x      = (const float*)d_in[0];
    const int*   ei     = (const int*)d_in[1];
    const float* hidden = (const float*)d_in[2];
    const float* gw     = (const float*)d_in[3];
    const float* gb     = (const float*)d_in[4];
    const float* w_ih   = (const float*)d_in[5];
    const float* w_hh   = (const float*)d_in[6];
    const float* b_ih   = (const float*)d_in[7];
    const float* b_hh   = (const float*)d_in[8];
    float* out = (float*)d_out;

    const int N = in_sizes[0] / D;   // 16384
    const int E = in_sizes[1] / 2;   // 262144

    // ws layout (floats): deg[16k] dinv[16k] hx[1024 u32] | gcn[N*D] | gi[N*3H]
    float* ws   = (float*)d_ws;
    float* deg  = ws;
    float* dinv = ws + 16384;
    unsigned* hx = (unsigned*)(ws + 32768);
    float* gcn  = ws + 65536;
    float* gi   = gcn + (size_t)N * D;
    float* xw   = gi;   // alias: xw dies before gi is written

    deg_init<<<(N + 255) / 256, 256, 0, stream>>>(deg, N);
    deg_count<<<(E + 255) / 256, 256, 0, stream>>>(ei, deg, E);
    deg_inv<<<(N + 255) / 256, 256, 0, stream>>>(deg, dinv, N);

    gemm64<false, false><<<dim3(H / 64, N / 64), 256, 0, stream>>>(
        x, gw, nullptr, xw, N, H, D);

    gcn_init<<<N, 512, 0, stream>>>(xw, dinv, gb, gcn, N);
    scatter_edges<<<E, 512, 0, stream>>>(ei, xw, dinv, gcn, E);

    gemm64<true, true><<<dim3(G3 / 64, N / 64), 256, 0, stream>>>(
        gcn, w_ih, b_ih, gi, N, G3, H);

    gru_init<<<1, 512, 0, stream>>>(hidden, hx);
    gru_kernel<<<GRU_WGS, GRU_THREADS, 0, stream>>>(
        gi, w_hh, b_hh, hx, out, N);
}

// Round 7
// 50783.279 us; speedup vs baseline: 1.4085x; 1.4085x over previous
//
#include <hip/hip_runtime.h>
#include <hip/hip_bf16.h>
#include <math.h>

#define D 512
#define H 512
#define G3 1536
#define GRU_WGS 32
#define GRU_THREADS 512   // 8 waves/WG ; wave owns 2 h-elements

__device__ __forceinline__ float sigmoidf_(float x) {
    return __fdividef(1.0f, 1.0f + __expf(-x));
}
__device__ __forceinline__ float tanhf_(float x) {
    return 1.0f - 2.0f * __fdividef(1.0f, 1.0f + __expf(2.0f * x));
}

// ---------------- degree / norm ----------------
__global__ void deg_init(float* deg, int N) {
    int i = blockIdx.x * blockDim.x + threadIdx.x;
    if (i < N) deg[i] = 2.0f;   // two self loops per node
}
__global__ void deg_count(const int* __restrict__ ei, float* deg, int E) {
    int e = blockIdx.x * blockDim.x + threadIdx.x;
    if (e < E) atomicAdd(&deg[ei[E + e]], 1.0f);
}
__global__ void deg_inv(const float* __restrict__ deg, float* dinv, int N) {
    int i = blockIdx.x * blockDim.x + threadIdx.x;
    if (i < N) dinv[i] = rsqrtf(deg[i]);
}

// ---------------- f32 tiled GEMM ----------------
template<bool NT, bool BIAS>
__global__ __launch_bounds__(256) void gemm64(
    const float* __restrict__ A, const float* __restrict__ B,
    const float* __restrict__ bias, float* __restrict__ C,
    int M, int N, int K)
{
    __shared__ float As[16][68];
    __shared__ float Bs[16][68];
    const int tid = threadIdx.x;
    const int tx = tid & 15, ty = tid >> 4;
    const int bm = blockIdx.y * 64, bn = blockIdx.x * 64;
    float acc[4][4] = {};
    for (int k0 = 0; k0 < K; k0 += 16) {
        #pragma unroll
        for (int l = 0; l < 4; ++l) {
            int idx = tid + l * 256;
            int m = idx >> 4, kk = idx & 15;
            As[kk][m] = A[(size_t)(bm + m) * K + (k0 + kk)];
            if (NT) {
                int n = idx >> 4, k2 = idx & 15;
                Bs[k2][n] = B[(size_t)(bn + n) * K + (k0 + k2)];
            } else {
                int k2 = idx >> 6, n = idx & 63;
                Bs[k2][n] = B[(size_t)(k0 + k2) * N + (bn + n)];
            }
        }
        __syncthreads();
        #pragma unroll
        for (int kk = 0; kk < 16; ++kk) {
            float4 av = *(const float4*)&As[kk][ty * 4];
            float4 bv = *(const float4*)&Bs[kk][tx * 4];
            float a[4] = {av.x, av.y, av.z, av.w};
            float b[4] = {bv.x, bv.y, bv.z, bv.w};
            #pragma unroll
            for (int i = 0; i < 4; ++i)
                #pragma unroll
                for (int j = 0; j < 4; ++j)
                    acc[i][j] = fmaf(a[i], b[j], acc[i][j]);
        }
        __syncthreads();
    }
    #pragma unroll
    for (int i = 0; i < 4; ++i)
        #pragma unroll
        for (int j = 0; j < 4; ++j) {
            float v = acc[i][j];
            if (BIAS) v += bias[bn + tx * 4 + j];
            C[(size_t)(bm + ty * 4 + i) * N + (bn + tx * 4 + j)] = v;
        }
}

// ---------------- GCN aggregation ----------------
__global__ void gcn_init(const float* __restrict__ xw, const float* __restrict__ dinv,
                         const float* __restrict__ bias, float* __restrict__ gcn, int N) {
    int n = blockIdx.x;
    int k = threadIdx.x;
    float di = dinv[n];
    gcn[(size_t)n * D + k] = bias[k] + 2.0f * di * di * xw[(size_t)n * D + k];
}
__global__ void scatter_edges(const int* __restrict__ ei, const float* __restrict__ xw,
                              const float* __restrict__ dinv, float* __restrict__ gcn, int E) {
    int e = blockIdx.x;
    int row = ei[e], col = ei[E + e];
    float norm = dinv[row] * dinv[col];
    int k = threadIdx.x;
    atomicAdd(&gcn[(size_t)col * D + k], norm * xw[(size_t)row * D + k]);
}

// ---------------- GRU ----------------
// h exchange: hx[2][512] of u32. Value = f32 h with its 2 mantissa LSBs
// replaced by (step_tag & 3). Each 4B word is self-validating -> single
// dword relaxed agent loads/stores, no fences. Tag noise <= 4.8e-7.
__global__ void gru_init(const float* __restrict__ hidden, unsigned* hx) {
    int i = threadIdx.x;           // 512 threads
    hx[i] = __float_as_uint(hidden[i]) & ~3u;  // slot 0: h_0, tag 0
    hx[H + i] = 2u;                            // slot 1: tag 2, never matches tag 1
}

// 32 WGs x 512 threads. Poll pattern = R3 (thread tid polls word tid ->
// LDS broadcast: 32 fabric reads/word/round, minimal congestion).
// Compute pattern = R6 (wave owns elements e0=wg*16+2*wid, e0+1; 6 rows in
// regs; in-wave butterfly; lane0 gates+publish; h_old/gi carried in regs).
// ONE raw barrier per step (lgkmcnt only - in-flight global stores don't
// gate it). LDS double-buffered by t&1.
__global__ __launch_bounds__(GRU_THREADS, 1) void gru_kernel(
    const float* __restrict__ gi, const float* __restrict__ w_hh,
    const float* __restrict__ b_hh, unsigned* hx,
    float* __restrict__ out, int T)
{
    const int wg = blockIdx.x;
    const int tid = threadIdx.x;
    const int wid = tid >> 6;
    const int lane = tid & 63;
    const int e0 = wg * 16 + 2 * wid;   // first of this wave's 2 elements

    __shared__ unsigned h_lds[2][H];

    // rows r: gate g=r>>1 (0=r,1=z,2=n), element offset r&1
    float w_reg[6][8];
    float bhh[6];
    #pragma unroll
    for (int r = 0; r < 6; ++r) {
        int grow = (r >> 1) * H + e0 + (r & 1);
        bhh[r] = b_hh[grow];
        #pragma unroll
        for (int m = 0; m < 8; ++m)
            w_reg[r][m] = w_hh[(size_t)grow * H + lane + 64 * m];
    }

    // lane-0 carried state: previous h for my 2 elements + current-step gi.
    float hold0 = __uint_as_float(hx[e0]);       // seed words: tag bits zero
    float hold1 = __uint_as_float(hx[e0 + 1]);
    float2 g_r = *(const float2*)&gi[e0];
    float2 g_z = *(const float2*)&gi[H + e0];
    float2 g_n = *(const float2*)&gi[2 * H + e0];

    for (int t = 0; t < T; ++t) {
        const int sl = t & 1;
        // ---- poll my ONE word, stage into LDS ----
        {
            const unsigned want = (unsigned)t & 3u;
            unsigned* p = &hx[sl * H + tid];
            unsigned v = __hip_atomic_load(p, __ATOMIC_RELAXED,
                                           __HIP_MEMORY_SCOPE_AGENT);
            while ((v & 3u) != want) {
                __builtin_amdgcn_s_sleep(1);
                v = __hip_atomic_load(p, __ATOMIC_RELAXED,
                                      __HIP_MEMORY_SCOPE_AGENT);
            }
            h_lds[sl][tid] = v;
        }
        // LDS writes visible to all waves; don't drain vmem (out/publish/gi
        // stores+loads stay in flight).
        asm volatile("s_waitcnt lgkmcnt(0)" ::: "memory");
        __builtin_amdgcn_s_barrier();

        // ---- each wave: read h, 6 dots, butterfly ----
        float hr[8];
        #pragma unroll
        for (int m = 0; m < 8; ++m)
            hr[m] = __uint_as_float(h_lds[sl][lane + 64 * m]);

        float acc[6];
        #pragma unroll
        for (int r = 0; r < 6; ++r) {
            float s = 0.f;
            #pragma unroll
            for (int m = 0; m < 8; ++m)
                s = fmaf(w_reg[r][m], hr[m], s);
            acc[r] = s;
        }
        #pragma unroll
        for (int off = 32; off; off >>= 1) {
            #pragma unroll
            for (int r = 0; r < 6; ++r)
                acc[r] += __shfl_xor(acc[r], off, 64);
        }

        // ---- lane 0: gates, publish, out, gi prefetch ----
        if (lane == 0) {
            float2 ngr, ngz, ngn;
            if (t + 1 < T) {   // issue next-step gi loads first (overlap)
                const float* gb2 = gi + (size_t)(t + 1) * G3;
                ngr = *(const float2*)&gb2[e0];
                ngz = *(const float2*)&gb2[H + e0];
                ngn = *(const float2*)&gb2[2 * H + e0];
            } else { ngr = g_r; ngz = g_z; ngn = g_n; }

            float rg0 = sigmoidf_(g_r.x + acc[0] + bhh[0]);
            float rg1 = sigmoidf_(g_r.y + acc[1] + bhh[1]);
            float zg0 = sigmoidf_(g_z.x + acc[2] + bhh[2]);
            float zg1 = sigmoidf_(g_z.y + acc[3] + bhh[3]);
            float ng0 = tanhf_(g_n.x + rg0 * (acc[4] + bhh[4]));
            float ng1 = tanhf_(g_n.y + rg1 * (acc[5] + bhh[5]));
            float h0 = ng0 + zg0 * (hold0 - ng0);
            float h1 = ng1 + zg1 * (hold1 - ng1);

            unsigned p0 = (__float_as_uint(h0) & ~3u) | ((unsigned)(t + 1) & 3u);
            unsigned p1 = (__float_as_uint(h1) & ~3u) | ((unsigned)(t + 1) & 3u);
            unsigned long long pv = ((unsigned long long)p1 << 32) | p0;
            __hip_atomic_store((unsigned long long*)&hx[((t + 1) & 1) * H + e0], pv,
                               __ATOMIC_RELAXED, __HIP_MEMORY_SCOPE_AGENT);

            *(float2*)&out[(size_t)t * H + e0] = make_float2(h0, h1);
            if (t == T - 1)
                *(float2*)&out[(size_t)T * H + e0] = make_float2(h0, h1);

            hold0 = h0; hold1 = h1;
            g_r = ngr; g_z = ngz; g_n = ngn;
        }
    }
}

// ---------------- launcher ----------------
extern "C" void kernel_launch(void* const* d_in, const int* in_sizes, int n_in,
                              void* d_out, int out_size, void* d_ws, size_t ws_size,
                              hipStream_t stream) {
    const float* x      = (const float*)d_in[0];
    const int*   ei     = (const int*)d_in[1];
    const float* hidden = (const float*)d_in[2];
    const float* gw     = (const float*)d_in[3];
    const float* gb     = (const float*)d_in[4];
    const float* w_ih   = (const float*)d_in[5];
    const float* w_hh   = (const float*)d_in[6];
    const float* b_ih   = (const float*)d_in[7];
    const float* b_hh   = (const float*)d_in[8];
    float* out = (float*)d_out;

    const int N = in_sizes[0] / D;   // 16384
    const int E = in_sizes[1] / 2;   // 262144

    // ws layout (floats): deg[16k] dinv[16k] hx[1024 u32] | gcn[N*D] | gi[N*3H]
    float* ws   = (float*)d_ws;
    float* deg  = ws;
    float* dinv = ws + 16384;
    unsigned* hx = (unsigned*)(ws + 32768);
    float* gcn  = ws + 65536;
    float* gi   = gcn + (size_t)N * D;
    float* xw   = gi;   // alias: xw dies before gi is written

    deg_init<<<(N + 255) / 256, 256, 0, stream>>>(deg, N);
    deg_count<<<(E + 255) / 256, 256, 0, stream>>>(ei, deg, E);
    deg_inv<<<(N + 255) / 256, 256, 0, stream>>>(deg, dinv, N);

    gemm64<false, false><<<dim3(H / 64, N / 64), 256, 0, stream>>>(
        x, gw, nullptr, xw, N, H, D);

    gcn_init<<<N, 512, 0, stream>>>(xw, dinv, gb, gcn, N);
    scatter_edges<<<E, 512, 0, stream>>>(ei, xw, dinv, gcn, E);

    gemm64<true, true><<<dim3(G3 / 64, N / 64), 256, 0, stream>>>(
        gcn, w_ih, b_ih, gi, N, G3, H);

    gru_init<<<1, 512, 0, stream>>>(hidden, hx);
    gru_kernel<<<GRU_WGS, GRU_THREADS, 0, stream>>>(
        gi, w_hh, b_hh, hx, out, N);
}